// Round 1
// baseline (9427.760 us; speedup 1.0000x reference)
//
#include <hip/hip_runtime.h>
#include <math.h>

// ExperimentalModel_1752346656819: 4-stage dynamic-conv decoder, fp32 end-to-end.
// B=64, C=8, L=32, R=16. Stages: 16->32->64->128->256, then dyn 1x1 conv to 3 ch.

#define BLK 256
#define EF 2.7182818284590452f

struct W1Args { const float* M[12]; float* out[12]; };
struct W2Args { const float* W[4]; const float* u[4]; const float* v[4]; float* out[4]; };

__device__ __forceinline__ float dln_one(float y, float m){
  float a = fabsf(y) - m;                       // a = |y| - min(|y|) >= 0
  float v = logf(logf(a + EF) + 0.01f);
  return (y > 0.0f) ? v : -v;                   // sign: where(y>0, 1, -1)
}

__global__ void gather_ctx_kernel(const int* __restrict__ ids,
                                  const float* __restrict__ cache,
                                  float* __restrict__ ctx){
  int e = blockIdx.x*blockDim.x + threadIdx.x;
  if (e < 64*32){
    int b = e >> 5, l = e & 31;
    ctx[e] = cache[(size_t)ids[b]*32 + l];
  }
}

__global__ void gather_x_kernel(const int* __restrict__ ids,
                                const float* __restrict__ lat,
                                float* __restrict__ A, int b0, int nb){
  int total = nb*2048;                           // 8*16*16 per sample
  int e = blockIdx.x*blockDim.x + threadIdx.x;
  if (e < total){
    int bl = e >> 11;
    int r  = e & 2047;
    A[e] = lat[(size_t)ids[b0+bl]*2048 + r];
  }
}

// out[s,b,k] = sum_l ctx[b,l] * M[s,l,k]   (u, v and biases for all convs)
__global__ void w1_kernel(const float* __restrict__ ctx, W1Args args){
  const int S[12] = {4,4,4,4,4,4,4,4,4,1,1,1};
  const int K[12] = {128,1152,128,2048,128,3200,8,8,8,48,128,3};
  int tid = blockIdx.x*blockDim.x + threadIdx.x;
  int nth = gridDim.x*blockDim.x;
  for (int seg = 0; seg < 12; ++seg){
    const float* M = args.M[seg];
    float* out = args.out[seg];
    int Ks = K[seg];
    int total = S[seg]*64*Ks;
    for (int e = tid; e < total; e += nth){
      int k = e % Ks;
      int b = (e / Ks) % 64;
      int s = e / (Ks*64);
      const float* Ms = M + (size_t)s*32*Ks + k;
      const float* cb = ctx + b*32;
      float acc = 0.f;
      #pragma unroll
      for (int l = 0; l < 32; ++l) acc += cb[l]*Ms[(size_t)l*Ks];
      out[e] = acc;
    }
  }
}

// w[s,b,o,k] = W[s,o,k] * (1 + sum_r u[s,b,r*O+o]*v[s,b,r*K+k] + 1e-3)
__global__ void w2_kernel(W2Args args){
  const int S[4] = {4,4,4,1};
  const int O[4] = {8,8,8,3};
  const int K[4] = {72,128,200,8};
  int tid = blockIdx.x*blockDim.x + threadIdx.x;
  int nth = gridDim.x*blockDim.x;
  for (int seg = 0; seg < 4; ++seg){
    int Os = O[seg], Ks = K[seg];
    int total = S[seg]*64*Os*Ks;
    const float* Wt = args.W[seg];
    const float* u = args.u[seg];
    const float* v = args.v[seg];
    float* out = args.out[seg];
    for (int e = tid; e < total; e += nth){
      int k = e % Ks;
      int o = (e/Ks) % Os;
      int b = (e/(Ks*Os)) % 64;
      int s = e/(Ks*Os*64);
      const float* us = u + (size_t)(s*64+b)*16*Os;
      const float* vs = v + (size_t)(s*64+b)*16*Ks;
      float mod = 0.f;
      #pragma unroll
      for (int r = 0; r < 16; ++r) mod += us[r*Os+o]*vs[r*Ks+k];
      out[e] = Wt[(size_t)(s*Os+o)*Ks + k] * (1.0f + mod + 1e-3f);
    }
  }
}

// 3x3 conv (pad 1) + per-map min + dln. One block per (b,o) map.
__global__ void __launch_bounds__(BLK) convr_dln_kernel(
    const float* __restrict__ x, const float* __restrict__ wall,
    const float* __restrict__ ball, float* __restrict__ out,
    int H, int b0, int s){
  __shared__ float wsm[73];
  __shared__ float red[BLK];
  const int map = blockIdx.x;
  const int bl = map >> 3, o = map & 7;
  const int bg = b0 + bl;
  const float* wp = wall + ((size_t)((s*64+bg)*8 + o))*72;
  if (threadIdx.x < 72) wsm[threadIdx.x] = wp[threadIdx.x];
  if (threadIdx.x == 0) wsm[72] = ball[(s*64+bg)*8 + o];
  __syncthreads();
  const int HW = H*H;
  const float* xb = x + (size_t)bl*8*HW;
  float* ob = out + (size_t)map*HW;
  float lmin = 3.4e38f;
  for (int px = threadIdx.x; px < HW; px += BLK){
    int h = px / H, w = px - h*H;
    float acc = wsm[72];
    #pragma unroll
    for (int p = 0; p < 3; ++p){
      int hh = h + p - 1;
      if ((unsigned)hh >= (unsigned)H) continue;
      #pragma unroll
      for (int q = 0; q < 3; ++q){
        int ww = w + q - 1;
        if ((unsigned)ww >= (unsigned)H) continue;
        const float* xp = xb + hh*H + ww;
        #pragma unroll
        for (int i = 0; i < 8; ++i) acc += wsm[i*9 + p*3 + q]*xp[(size_t)i*HW];
      }
    }
    ob[px] = acc;
    lmin = fminf(lmin, fabsf(acc));
  }
  red[threadIdx.x] = lmin; __syncthreads();
  for (int t = BLK/2; t > 0; t >>= 1){
    if (threadIdx.x < t) red[threadIdx.x] = fminf(red[threadIdx.x], red[threadIdx.x+t]);
    __syncthreads();
  }
  float m = red[0];
  for (int px = threadIdx.x; px < HW; px += BLK) ob[px] = dln_one(ob[px], m);
}

// 4x4 stride-2 transposed conv of (-x) (pad 1) + min + dln. Block per map; out 2H x 2H.
__global__ void __launch_bounds__(BLK) convt_dln_kernel(
    const float* __restrict__ x, const float* __restrict__ wall,
    const float* __restrict__ ball, float* __restrict__ out,
    int H, int b0, int s){
  __shared__ float wsm[129];
  __shared__ float red[BLK];
  const int map = blockIdx.x;
  const int bl = map >> 3, o = map & 7;
  const int bg = b0 + bl;
  const float* wp = wall + ((size_t)((s*64+bg)*8 + o))*128;
  for (int t = threadIdx.x; t < 128; t += BLK) wsm[t] = wp[t];
  if (threadIdx.x == 0) wsm[128] = ball[(s*64+bg)*8 + o];
  __syncthreads();
  const int Ho = 2*H, HWo = Ho*Ho, HW = H*H;
  const float* xb = x + (size_t)bl*8*HW;
  float* ob = out + (size_t)map*HWo;
  float lmin = 3.4e38f;
  for (int px = threadIdx.x; px < HWo; px += BLK){
    int y = px / Ho, xx = px - y*Ho;
    // valid (p,h): y even -> (1, y/2), (3, y/2-1); y odd -> (0,(y+1)/2), (2,(y-1)/2)
    int p0, h0, p1, h1, q0, w0, q1, w1;
    if (y & 1){ p0 = 0; h0 = (y+1) >> 1; p1 = 2; h1 = (y-1) >> 1; }
    else      { p0 = 1; h0 = y >> 1;     p1 = 3; h1 = (y >> 1) - 1; }
    if (xx & 1){ q0 = 0; w0 = (xx+1) >> 1; q1 = 2; w1 = (xx-1) >> 1; }
    else       { q0 = 1; w0 = xx >> 1;     q1 = 3; w1 = (xx >> 1) - 1; }
    float acc = wsm[128];                       // bias; input is -x so subtract taps
    #pragma unroll
    for (int a2 = 0; a2 < 2; ++a2){
      int p = a2 ? p1 : p0, h = a2 ? h1 : h0;
      if ((unsigned)h >= (unsigned)H) continue;
      #pragma unroll
      for (int b2 = 0; b2 < 2; ++b2){
        int q = b2 ? q1 : q0, w = b2 ? w1 : w0;
        if ((unsigned)w >= (unsigned)H) continue;
        const float* xp = xb + h*H + w;
        int wi = p*4 + q;
        #pragma unroll
        for (int i = 0; i < 8; ++i) acc -= wsm[i*16 + wi]*xp[(size_t)i*HW];
      }
    }
    ob[px] = acc;
    lmin = fminf(lmin, fabsf(acc));
  }
  red[threadIdx.x] = lmin; __syncthreads();
  for (int t = BLK/2; t > 0; t >>= 1){
    if (threadIdx.x < t) red[threadIdx.x] = fminf(red[threadIdx.x], red[threadIdx.x+t]);
    __syncthreads();
  }
  float m = red[0];
  for (int px = threadIdx.x; px < HWo; px += BLK) ob[px] = dln_one(ob[px], m);
}

// bilinear 2x upsample of log(|x|+1): half-pixel centers, 0.75/0.25, edge clamp.
__global__ void uplog_kernel(const float* __restrict__ x, float* __restrict__ out,
                             int H, int total){
  int Ho = 2*H, HWo = Ho*Ho, HW = H*H;
  for (int e = blockIdx.x*blockDim.x + threadIdx.x; e < total; e += gridDim.x*blockDim.x){
    int m = e / HWo;
    int px = e - m*HWo;
    int y = px / Ho, xx = px - y*Ho;
    const float* xm = x + (size_t)m*HW;
    int jy = y >> 1, jx = xx >> 1;
    int ny = (y & 1)  ? ((jy+1 < H) ? jy+1 : H-1) : ((jy > 0) ? jy-1 : 0);
    int nx = (xx & 1) ? ((jx+1 < H) ? jx+1 : H-1) : ((jx > 0) ? jx-1 : 0);
    float f00 = logf(fabsf(xm[jy*H + jx]) + 1.0f);
    float f01 = logf(fabsf(xm[jy*H + nx]) + 1.0f);
    float f10 = logf(fabsf(xm[ny*H + jx]) + 1.0f);
    float f11 = logf(fabsf(xm[ny*H + nx]) + 1.0f);
    out[e] = 0.5625f*f00 + 0.1875f*(f01 + f10) + 0.0625f*f11;
  }
}

// 5x5 conv (pad 2) + min + dln. Block per (b,o) map of Hi x Hi.
__global__ void __launch_bounds__(BLK) convm_dln_kernel(
    const float* __restrict__ x, const float* __restrict__ wall,
    const float* __restrict__ ball, float* __restrict__ out,
    int Hi, int b0, int s){
  __shared__ float wsm[201];
  __shared__ float red[BLK];
  const int map = blockIdx.x;
  const int bl = map >> 3, o = map & 7;
  const int bg = b0 + bl;
  const float* wp = wall + ((size_t)((s*64+bg)*8 + o))*200;
  for (int t = threadIdx.x; t < 200; t += BLK) wsm[t] = wp[t];
  if (threadIdx.x == 0) wsm[200] = ball[(s*64+bg)*8 + o];
  __syncthreads();
  const int HW = Hi*Hi;
  const float* xb = x + (size_t)bl*8*HW;
  float* ob = out + (size_t)map*HW;
  float lmin = 3.4e38f;
  for (int px = threadIdx.x; px < HW; px += BLK){
    int h = px / Hi, w = px - h*Hi;
    float acc = wsm[200];
    #pragma unroll
    for (int p = 0; p < 5; ++p){
      int hh = h + p - 2;
      if ((unsigned)hh >= (unsigned)Hi) continue;
      #pragma unroll
      for (int q = 0; q < 5; ++q){
        int ww = w + q - 2;
        if ((unsigned)ww >= (unsigned)Hi) continue;
        const float* xp = xb + hh*Hi + ww;
        #pragma unroll
        for (int i = 0; i < 8; ++i) acc += wsm[i*25 + p*5 + q]*xp[(size_t)i*HW];
      }
    }
    ob[px] = acc;
    lmin = fminf(lmin, fabsf(acc));
  }
  red[threadIdx.x] = lmin; __syncthreads();
  for (int t = BLK/2; t > 0; t >>= 1){
    if (threadIdx.x < t) red[threadIdx.x] = fminf(red[threadIdx.x], red[threadIdx.x+t]);
    __syncthreads();
  }
  float m = red[0];
  for (int px = threadIdx.x; px < HW; px += BLK) ob[px] = dln_one(ob[px], m);
}

// next_x = (dln_r[nearest-up] + dln_t) * dln_m
__global__ void combine_kernel(const float* __restrict__ dr, const float* __restrict__ dt,
                               const float* __restrict__ dm, float* __restrict__ outx,
                               int H, int total){
  int Ho = 2*H, HWo = Ho*Ho, HW = H*H;
  for (int e = blockIdx.x*blockDim.x + threadIdx.x; e < total; e += gridDim.x*blockDim.x){
    int m = e / HWo;
    int px = e - m*HWo;
    int y = px / Ho, xx = px - y*Ho;
    float r = dr[(size_t)m*HW + (y >> 1)*H + (xx >> 1)];
    outx[e] = (r + dt[e]) * dm[e];
  }
}

// final dynamic 1x1 conv: 8 -> 3 channels, + bias, writes d_out with global b.
__global__ void final_kernel(const float* __restrict__ x, const float* __restrict__ wo,
                             const float* __restrict__ bo, float* __restrict__ out,
                             int b0, int total){
  for (int e = blockIdx.x*blockDim.x + threadIdx.x; e < total; e += gridDim.x*blockDim.x){
    int px = e & 65535;
    int t = e >> 16;
    int o = t % 3;
    int bl = t / 3;
    int bg = b0 + bl;
    const float* xb = x + ((size_t)bl*8)*65536 + px;
    const float* w = wo + bg*24 + o*8;
    float acc = bo[bg*3 + o];
    #pragma unroll
    for (int i = 0; i < 8; ++i) acc += w[i]*xb[(size_t)i*65536];
    out[((size_t)(bg*3 + o))*65536 + px] = acc;
  }
}

static inline int grid_for(long long total){
  long long g = (total + BLK - 1) / BLK;
  if (g > 16384) g = 16384;
  if (g < 1) g = 1;
  return (int)g;
}

extern "C" void kernel_launch(void* const* d_in, const int* in_sizes, int n_in,
                              void* d_out, int out_size, void* d_ws, size_t ws_size,
                              hipStream_t stream){
  (void)in_sizes; (void)n_in; (void)out_size;
  const int*   ids   = (const int*)d_in[0];
  const float* cache = (const float*)d_in[1];
  const float* lat   = (const float*)d_in[2];
  const float* Wr = (const float*)d_in[3];
  const float* Ur = (const float*)d_in[4];
  const float* Vr = (const float*)d_in[5];
  const float* Br = (const float*)d_in[6];
  const float* Wt = (const float*)d_in[7];
  const float* Ut = (const float*)d_in[8];
  const float* Vt = (const float*)d_in[9];
  const float* Bt = (const float*)d_in[10];
  const float* Wm = (const float*)d_in[11];
  const float* Um = (const float*)d_in[12];
  const float* Vm = (const float*)d_in[13];
  const float* Bm = (const float*)d_in[14];
  const float* Wo = (const float*)d_in[15];
  const float* Uo = (const float*)d_in[16];
  const float* Vo = (const float*)d_in[17];
  const float* Bo = (const float*)d_in[18];
  float* out = (float*)d_out;
  float* ws  = (float*)d_ws;

  // ---- ws layout (floats) ----
  size_t off = 0;
  auto alloc = [&](size_t n){ size_t o = off; off += n; return o; };
  size_t o_ctx = alloc(2048);
  size_t o_ur = alloc(4*64*128),  o_vr = alloc(4*64*1152);
  size_t o_ut = alloc(4*64*128),  o_vt = alloc(4*64*2048);
  size_t o_um = alloc(4*64*128),  o_vm = alloc(4*64*3200);
  size_t o_br = alloc(4*64*8), o_bt = alloc(4*64*8), o_bm = alloc(4*64*8);
  size_t o_uo = alloc(64*48), o_vo = alloc(64*128), o_bo = alloc(64*3);
  size_t o_wr = alloc(4*64*8*72), o_wt = alloc(4*64*8*128), o_wm = alloc(4*64*8*200);
  size_t o_wo = alloc(64*24);
  size_t small_end = off;

  // big buffers: A (x / next_x), B (dln_t), C1 (xup), C2 (dln_m) at 8*256*256/sample,
  // D (dln_r) at 8*128*128/sample. Chunk samples to fit ws.
  const size_t perS = 4*(size_t)524288 + 131072;
  size_t ws_f = ws_size / sizeof(float);
  int nb = 64;
  while (nb > 1 && small_end + (size_t)nb*perS > ws_f) nb >>= 1;

  size_t o_A  = small_end;
  size_t o_B  = o_A  + (size_t)nb*524288;
  size_t o_C1 = o_B  + (size_t)nb*524288;
  size_t o_C2 = o_C1 + (size_t)nb*524288;
  size_t o_D  = o_C2 + (size_t)nb*524288;

  gather_ctx_kernel<<<8, BLK, 0, stream>>>(ids, cache, ws + o_ctx);

  W1Args a1;
  a1.M[0]=Ur;  a1.out[0]=ws+o_ur;
  a1.M[1]=Vr;  a1.out[1]=ws+o_vr;
  a1.M[2]=Ut;  a1.out[2]=ws+o_ut;
  a1.M[3]=Vt;  a1.out[3]=ws+o_vt;
  a1.M[4]=Um;  a1.out[4]=ws+o_um;
  a1.M[5]=Vm;  a1.out[5]=ws+o_vm;
  a1.M[6]=Br;  a1.out[6]=ws+o_br;
  a1.M[7]=Bt;  a1.out[7]=ws+o_bt;
  a1.M[8]=Bm;  a1.out[8]=ws+o_bm;
  a1.M[9]=Uo;  a1.out[9]=ws+o_uo;
  a1.M[10]=Vo; a1.out[10]=ws+o_vo;
  a1.M[11]=Bo; a1.out[11]=ws+o_bo;
  w1_kernel<<<256, BLK, 0, stream>>>(ws + o_ctx, a1);

  W2Args a2;
  a2.W[0]=Wr; a2.u[0]=ws+o_ur; a2.v[0]=ws+o_vr; a2.out[0]=ws+o_wr;
  a2.W[1]=Wt; a2.u[1]=ws+o_ut; a2.v[1]=ws+o_vt; a2.out[1]=ws+o_wt;
  a2.W[2]=Wm; a2.u[2]=ws+o_um; a2.v[2]=ws+o_vm; a2.out[2]=ws+o_wm;
  a2.W[3]=Wo; a2.u[3]=ws+o_uo; a2.v[3]=ws+o_vo; a2.out[3]=ws+o_wo;
  w2_kernel<<<256, BLK, 0, stream>>>(a2);

  for (int b0 = 0; b0 < 64; b0 += nb){
    gather_x_kernel<<<grid_for((long long)nb*2048), BLK, 0, stream>>>(ids, lat, ws+o_A, b0, nb);
    int H = 16;
    for (int s = 0; s < 4; ++s){
      int Ho = 2*H;
      int maps = nb*8;
      long long totalo = (long long)maps*Ho*Ho;
      convr_dln_kernel<<<maps, BLK, 0, stream>>>(ws+o_A, ws+o_wr, ws+o_br, ws+o_D, H, b0, s);
      convt_dln_kernel<<<maps, BLK, 0, stream>>>(ws+o_A, ws+o_wt, ws+o_bt, ws+o_B, H, b0, s);
      uplog_kernel<<<grid_for(totalo), BLK, 0, stream>>>(ws+o_A, ws+o_C1, H, (int)totalo);
      convm_dln_kernel<<<maps, BLK, 0, stream>>>(ws+o_C1, ws+o_wm, ws+o_bm, ws+o_C2, Ho, b0, s);
      combine_kernel<<<grid_for(totalo), BLK, 0, stream>>>(ws+o_D, ws+o_B, ws+o_C2, ws+o_A, H, (int)totalo);
      H = Ho;
    }
    long long totalf = (long long)nb*3*65536;
    final_kernel<<<grid_for(totalf), BLK, 0, stream>>>(ws+o_A, ws+o_wo, ws+o_bo, out, b0, (int)totalf);
  }
}

// Round 2
// 4645.663 us; speedup vs baseline: 2.0294x; 2.0294x over previous
//
#include <hip/hip_runtime.h>
#include <math.h>

// ExperimentalModel_1752346656819: 4-stage dynamic-conv decoder, fp32 end-to-end.
// R1: strip-parallel convs + atomicMin per-map min + dln fused into combine.

#define BLK 256
#define EF 2.7182818284590452f

struct W1Args { const float* M[12]; float* out[12]; };
struct W2Args { const float* W[4]; const float* u[4]; const float* v[4]; float* out[4]; };

__device__ __forceinline__ float dln_one(float y, float m){
  float a = fabsf(y) - m;                       // a = |y| - min(|y|) >= 0
  float v = logf(logf(a + EF) + 0.01f);
  return (y > 0.0f) ? v : -v;
}

__global__ void gather_ctx_kernel(const int* __restrict__ ids,
                                  const float* __restrict__ cache,
                                  float* __restrict__ ctx){
  int e = blockIdx.x*blockDim.x + threadIdx.x;
  if (e < 64*32){
    int b = e >> 5, l = e & 31;
    ctx[e] = cache[(size_t)ids[b]*32 + l];
  }
}

__global__ void gather_x_kernel(const int* __restrict__ ids,
                                const float* __restrict__ lat,
                                float* __restrict__ A, int b0, int nb){
  int total = nb*2048;
  int e = blockIdx.x*blockDim.x + threadIdx.x;
  if (e < total){
    int bl = e >> 11;
    int r  = e & 2047;
    A[e] = lat[(size_t)ids[b0+bl]*2048 + r];
  }
}

__global__ void w1_kernel(const float* __restrict__ ctx, W1Args args){
  const int S[12] = {4,4,4,4,4,4,4,4,4,1,1,1};
  const int K[12] = {128,1152,128,2048,128,3200,8,8,8,48,128,3};
  int tid = blockIdx.x*blockDim.x + threadIdx.x;
  int nth = gridDim.x*blockDim.x;
  for (int seg = 0; seg < 12; ++seg){
    const float* M = args.M[seg];
    float* out = args.out[seg];
    int Ks = K[seg];
    int total = S[seg]*64*Ks;
    for (int e = tid; e < total; e += nth){
      int k = e % Ks;
      int b = (e / Ks) % 64;
      int s = e / (Ks*64);
      const float* Ms = M + (size_t)s*32*Ks + k;
      const float* cb = ctx + b*32;
      float acc = 0.f;
      #pragma unroll
      for (int l = 0; l < 32; ++l) acc += cb[l]*Ms[(size_t)l*Ks];
      out[e] = acc;
    }
  }
}

__global__ void w2_kernel(W2Args args){
  const int S[4] = {4,4,4,1};
  const int O[4] = {8,8,8,3};
  const int K[4] = {72,128,200,8};
  int tid = blockIdx.x*blockDim.x + threadIdx.x;
  int nth = gridDim.x*blockDim.x;
  for (int seg = 0; seg < 4; ++seg){
    int Os = O[seg], Ks = K[seg];
    int total = S[seg]*64*Os*Ks;
    const float* Wt = args.W[seg];
    const float* u = args.u[seg];
    const float* v = args.v[seg];
    float* out = args.out[seg];
    for (int e = tid; e < total; e += nth){
      int k = e % Ks;
      int o = (e/Ks) % Os;
      int b = (e/(Ks*Os)) % 64;
      int s = e/(Ks*Os*64);
      const float* us = u + (size_t)(s*64+b)*16*Os;
      const float* vs = v + (size_t)(s*64+b)*16*Ks;
      float mod = 0.f;
      #pragma unroll
      for (int r = 0; r < 16; ++r) mod += us[r*Os+o]*vs[r*Ks+k];
      out[e] = Wt[(size_t)(s*Os+o)*Ks + k] * (1.0f + mod + 1e-3f);
    }
  }
}

__global__ void init_min_kernel(unsigned* __restrict__ mn, int n){
  int e = blockIdx.x*blockDim.x + threadIdx.x;
  if (e < n) mn[e] = 0x7F800000u;   // +inf
}

__device__ __forceinline__ void block_min_commit(float lmin, unsigned* mnp, float* red){
  red[threadIdx.x] = lmin; __syncthreads();
  for (int t = BLK/2; t > 0; t >>= 1){
    if (threadIdx.x < t) red[threadIdx.x] = fminf(red[threadIdx.x], red[threadIdx.x+t]);
    __syncthreads();
  }
  if (threadIdx.x == 0) atomicMin(mnp, __float_as_uint(red[0]));
}

// 3x3 conv (pad 1), raw output + per-map min. Grid = maps*strips.
__global__ void __launch_bounds__(BLK) convr_kernel(
    const float* __restrict__ x, const float* __restrict__ wall,
    const float* __restrict__ ball, float* __restrict__ out,
    unsigned* __restrict__ mn, int H, int b0, int s, int strips){
  __shared__ float wsm[73];
  __shared__ float red[BLK];
  const int map = blockIdx.x / strips;
  const int strip = blockIdx.x - map*strips;
  const int bl = map >> 3, o = map & 7;
  const int bg = b0 + bl;
  const float* wp = wall + ((size_t)((s*64+bg)*8 + o))*72;
  if (threadIdx.x < 72) wsm[threadIdx.x] = wp[threadIdx.x];
  if (threadIdx.x == 0) wsm[72] = ball[(s*64+bg)*8 + o];
  __syncthreads();
  const int HW = H*H;
  const int chunk = (HW + strips - 1)/strips;
  const int p0 = strip*chunk;
  const int p1 = min(HW, p0 + chunk);
  const float* xb = x + (size_t)bl*8*HW;
  float* ob = out + (size_t)map*HW;
  float lmin = 3.4e38f;
  for (int px = p0 + threadIdx.x; px < p1; px += BLK){
    int h = px / H, w = px - h*H;
    float acc = wsm[72];
    #pragma unroll
    for (int p = 0; p < 3; ++p){
      int hh = h + p - 1;
      if ((unsigned)hh >= (unsigned)H) continue;
      #pragma unroll
      for (int q = 0; q < 3; ++q){
        int ww = w + q - 1;
        if ((unsigned)ww >= (unsigned)H) continue;
        const float* xp = xb + hh*H + ww;
        #pragma unroll
        for (int i = 0; i < 8; ++i) acc += wsm[i*9 + p*3 + q]*xp[(size_t)i*HW];
      }
    }
    ob[px] = acc;
    lmin = fminf(lmin, fabsf(acc));
  }
  block_min_commit(lmin, mn + map, red);
}

// 4x4 stride-2 transposed conv of (-x) (pad 1), raw out + min. out 2H x 2H.
__global__ void __launch_bounds__(BLK) convt_kernel(
    const float* __restrict__ x, const float* __restrict__ wall,
    const float* __restrict__ ball, float* __restrict__ out,
    unsigned* __restrict__ mn, int H, int b0, int s, int strips){
  __shared__ float wsm[129];
  __shared__ float red[BLK];
  const int map = blockIdx.x / strips;
  const int strip = blockIdx.x - map*strips;
  const int bl = map >> 3, o = map & 7;
  const int bg = b0 + bl;
  const float* wp = wall + ((size_t)((s*64+bg)*8 + o))*128;
  for (int t = threadIdx.x; t < 128; t += BLK) wsm[t] = wp[t];
  if (threadIdx.x == 0) wsm[128] = ball[(s*64+bg)*8 + o];
  __syncthreads();
  const int Ho = 2*H, HWo = Ho*Ho, HW = H*H;
  const int chunk = (HWo + strips - 1)/strips;
  const int p0 = strip*chunk;
  const int p1 = min(HWo, p0 + chunk);
  const float* xb = x + (size_t)bl*8*HW;
  float* ob = out + (size_t)map*HWo;
  float lmin = 3.4e38f;
  for (int px = p0 + threadIdx.x; px < p1; px += BLK){
    int y = px / Ho, xx = px - y*Ho;
    int pa0, h0, pa1, h1, qa0, w0, qa1, w1;
    if (y & 1){ pa0 = 0; h0 = (y+1) >> 1; pa1 = 2; h1 = (y-1) >> 1; }
    else      { pa0 = 1; h0 = y >> 1;     pa1 = 3; h1 = (y >> 1) - 1; }
    if (xx & 1){ qa0 = 0; w0 = (xx+1) >> 1; qa1 = 2; w1 = (xx-1) >> 1; }
    else       { qa0 = 1; w0 = xx >> 1;     qa1 = 3; w1 = (xx >> 1) - 1; }
    float acc = wsm[128];
    #pragma unroll
    for (int a2 = 0; a2 < 2; ++a2){
      int p = a2 ? pa1 : pa0, h = a2 ? h1 : h0;
      if ((unsigned)h >= (unsigned)H) continue;
      #pragma unroll
      for (int b2 = 0; b2 < 2; ++b2){
        int q = b2 ? qa1 : qa0, w = b2 ? w1 : w0;
        if ((unsigned)w >= (unsigned)H) continue;
        const float* xp = xb + h*H + w;
        int wi = p*4 + q;
        #pragma unroll
        for (int i = 0; i < 8; ++i) acc -= wsm[i*16 + wi]*xp[(size_t)i*HW];
      }
    }
    ob[px] = acc;
    lmin = fminf(lmin, fabsf(acc));
  }
  block_min_commit(lmin, mn + map, red);
}

// bilinear 2x upsample of log(|x|+1)
__global__ void uplog_kernel(const float* __restrict__ x, float* __restrict__ out,
                             int H, int total){
  int Ho = 2*H, HWo = Ho*Ho, HW = H*H;
  for (int e = blockIdx.x*blockDim.x + threadIdx.x; e < total; e += gridDim.x*blockDim.x){
    int m = e / HWo;
    int px = e - m*HWo;
    int y = px / Ho, xx = px - y*Ho;
    const float* xm = x + (size_t)m*HW;
    int jy = y >> 1, jx = xx >> 1;
    int ny = (y & 1)  ? ((jy+1 < H) ? jy+1 : H-1) : ((jy > 0) ? jy-1 : 0);
    int nx = (xx & 1) ? ((jx+1 < H) ? jx+1 : H-1) : ((jx > 0) ? jx-1 : 0);
    float f00 = logf(fabsf(xm[jy*H + jx]) + 1.0f);
    float f01 = logf(fabsf(xm[jy*H + nx]) + 1.0f);
    float f10 = logf(fabsf(xm[ny*H + jx]) + 1.0f);
    float f11 = logf(fabsf(xm[ny*H + nx]) + 1.0f);
    out[e] = 0.5625f*f00 + 0.1875f*(f01 + f10) + 0.0625f*f11;
  }
}

// 5x5 conv (pad 2), 4 px per thread (row groups), raw out + min. Grid = maps*strips.
__global__ void __launch_bounds__(BLK) convm_kernel(
    const float* __restrict__ x, const float* __restrict__ wall,
    const float* __restrict__ ball, float* __restrict__ out,
    unsigned* __restrict__ mn, int Hi, int b0, int s, int strips){
  __shared__ float wsm[201];
  __shared__ float red[BLK];
  const int map = blockIdx.x / strips;
  const int strip = blockIdx.x - map*strips;
  const int bl = map >> 3, o = map & 7;
  const int bg = b0 + bl;
  const float* wp = wall + ((size_t)((s*64+bg)*8 + o))*200;
  for (int t = threadIdx.x; t < 200; t += BLK) wsm[t] = wp[t];
  if (threadIdx.x == 0) wsm[200] = ball[(s*64+bg)*8 + o];
  __syncthreads();
  const int HW = Hi*Hi;
  const int G = HW >> 2;                        // 4-px groups (Hi % 4 == 0)
  const int chunk = (G + strips - 1)/strips;
  const int g0 = strip*chunk;
  const int g1 = min(G, g0 + chunk);
  const float* xb = x + (size_t)bl*8*HW;
  float* ob = out + (size_t)map*HW;
  float lmin = 3.4e38f;
  for (int g = g0 + threadIdx.x; g < g1; g += BLK){
    int base = g << 2;
    int h = base / Hi, w0 = base - h*Hi;        // w0 % 4 == 0, group stays in one row
    float a0, a1, a2, a3;
    a0 = a1 = a2 = a3 = wsm[200];
    #pragma unroll
    for (int p = 0; p < 5; ++p){
      int hh = h + p - 2;
      if ((unsigned)hh >= (unsigned)Hi) continue;
      const float* rowp = xb + hh*Hi;
      #pragma unroll
      for (int i = 0; i < 8; ++i){
        const float* rp = rowp + (size_t)i*HW;
        float c[8];
        #pragma unroll
        for (int q = 0; q < 8; ++q){
          int ww = w0 + q - 2;
          c[q] = ((unsigned)ww < (unsigned)Hi) ? rp[ww] : 0.f;
        }
        const float* wv = wsm + i*25 + p*5;
        #pragma unroll
        for (int q = 0; q < 5; ++q){
          float wq = wv[q];
          a0 += wq*c[q];
          a1 += wq*c[q+1];
          a2 += wq*c[q+2];
          a3 += wq*c[q+3];
        }
      }
    }
    ob[base+0] = a0; ob[base+1] = a1; ob[base+2] = a2; ob[base+3] = a3;
    lmin = fminf(lmin, fabsf(a0));
    lmin = fminf(lmin, fabsf(a1));
    lmin = fminf(lmin, fabsf(a2));
    lmin = fminf(lmin, fabsf(a3));
  }
  block_min_commit(lmin, mn + map, red);
}

// next_x = (dln(Dr)[nearest-up] + dln(Dt)) * dln(Dm)
__global__ void combine_kernel(const float* __restrict__ dr, const float* __restrict__ dt,
                               const float* __restrict__ dm,
                               const unsigned* __restrict__ mn, int maps,
                               float* __restrict__ outx, int H, int total){
  int Ho = 2*H, HWo = Ho*Ho, HW = H*H;
  for (int e = blockIdx.x*blockDim.x + threadIdx.x; e < total; e += gridDim.x*blockDim.x){
    int m = e / HWo;
    int px = e - m*HWo;
    int y = px / Ho, xx = px - y*Ho;
    float mr = __uint_as_float(mn[m]);
    float mt = __uint_as_float(mn[maps + m]);
    float mm = __uint_as_float(mn[2*maps + m]);
    float r = dln_one(dr[(size_t)m*HW + (y >> 1)*H + (xx >> 1)], mr);
    float t = dln_one(dt[e], mt);
    float mv = dln_one(dm[e], mm);
    outx[e] = (r + t) * mv;
  }
}

__global__ void final_kernel(const float* __restrict__ x, const float* __restrict__ wo,
                             const float* __restrict__ bo, float* __restrict__ out,
                             int b0, int total){
  for (int e = blockIdx.x*blockDim.x + threadIdx.x; e < total; e += gridDim.x*blockDim.x){
    int px = e & 65535;
    int t = e >> 16;
    int o = t % 3;
    int bl = t / 3;
    int bg = b0 + bl;
    const float* xb = x + ((size_t)bl*8)*65536 + px;
    const float* w = wo + bg*24 + o*8;
    float acc = bo[bg*3 + o];
    #pragma unroll
    for (int i = 0; i < 8; ++i) acc += w[i]*xb[(size_t)i*65536];
    out[((size_t)(bg*3 + o))*65536 + px] = acc;
  }
}

static inline int grid_for(long long total){
  long long g = (total + BLK - 1) / BLK;
  if (g > 16384) g = 16384;
  if (g < 1) g = 1;
  return (int)g;
}

extern "C" void kernel_launch(void* const* d_in, const int* in_sizes, int n_in,
                              void* d_out, int out_size, void* d_ws, size_t ws_size,
                              hipStream_t stream){
  (void)in_sizes; (void)n_in; (void)out_size;
  const int*   ids   = (const int*)d_in[0];
  const float* cache = (const float*)d_in[1];
  const float* lat   = (const float*)d_in[2];
  const float* Wr = (const float*)d_in[3];
  const float* Ur = (const float*)d_in[4];
  const float* Vr = (const float*)d_in[5];
  const float* Br = (const float*)d_in[6];
  const float* Wt = (const float*)d_in[7];
  const float* Ut = (const float*)d_in[8];
  const float* Vt = (const float*)d_in[9];
  const float* Bt = (const float*)d_in[10];
  const float* Wm = (const float*)d_in[11];
  const float* Um = (const float*)d_in[12];
  const float* Vm = (const float*)d_in[13];
  const float* Bm = (const float*)d_in[14];
  const float* Wo = (const float*)d_in[15];
  const float* Uo = (const float*)d_in[16];
  const float* Vo = (const float*)d_in[17];
  const float* Bo = (const float*)d_in[18];
  float* out = (float*)d_out;
  float* ws  = (float*)d_ws;

  size_t off = 0;
  auto alloc = [&](size_t n){ size_t o = off; off += n; return o; };
  size_t o_ctx = alloc(2048);
  size_t o_ur = alloc(4*64*128),  o_vr = alloc(4*64*1152);
  size_t o_ut = alloc(4*64*128),  o_vt = alloc(4*64*2048);
  size_t o_um = alloc(4*64*128),  o_vm = alloc(4*64*3200);
  size_t o_br = alloc(4*64*8), o_bt = alloc(4*64*8), o_bm = alloc(4*64*8);
  size_t o_uo = alloc(64*48), o_vo = alloc(64*128), o_bo = alloc(64*3);
  size_t o_wr = alloc(4*64*8*72), o_wt = alloc(4*64*8*128), o_wm = alloc(4*64*8*200);
  size_t o_wo = alloc(64*24);
  size_t o_mn = alloc(3*512);            // min arrays (as unsigned)
  size_t small_end = off;

  const size_t perS = 4*(size_t)524288 + 131072;
  size_t ws_f = ws_size / sizeof(float);
  int nb = 64;
  while (nb > 1 && small_end + (size_t)nb*perS > ws_f) nb >>= 1;

  size_t o_A  = small_end;
  size_t o_B  = o_A  + (size_t)nb*524288;   // Dt
  size_t o_C1 = o_B  + (size_t)nb*524288;   // xup
  size_t o_C2 = o_C1 + (size_t)nb*524288;   // Dm
  size_t o_D  = o_C2 + (size_t)nb*524288;   // Dr
  unsigned* mn = (unsigned*)(ws + o_mn);

  gather_ctx_kernel<<<8, BLK, 0, stream>>>(ids, cache, ws + o_ctx);

  W1Args a1;
  a1.M[0]=Ur;  a1.out[0]=ws+o_ur;
  a1.M[1]=Vr;  a1.out[1]=ws+o_vr;
  a1.M[2]=Ut;  a1.out[2]=ws+o_ut;
  a1.M[3]=Vt;  a1.out[3]=ws+o_vt;
  a1.M[4]=Um;  a1.out[4]=ws+o_um;
  a1.M[5]=Vm;  a1.out[5]=ws+o_vm;
  a1.M[6]=Br;  a1.out[6]=ws+o_br;
  a1.M[7]=Bt;  a1.out[7]=ws+o_bt;
  a1.M[8]=Bm;  a1.out[8]=ws+o_bm;
  a1.M[9]=Uo;  a1.out[9]=ws+o_uo;
  a1.M[10]=Vo; a1.out[10]=ws+o_vo;
  a1.M[11]=Bo; a1.out[11]=ws+o_bo;
  w1_kernel<<<256, BLK, 0, stream>>>(ws + o_ctx, a1);

  W2Args a2;
  a2.W[0]=Wr; a2.u[0]=ws+o_ur; a2.v[0]=ws+o_vr; a2.out[0]=ws+o_wr;
  a2.W[1]=Wt; a2.u[1]=ws+o_ut; a2.v[1]=ws+o_vt; a2.out[1]=ws+o_wt;
  a2.W[2]=Wm; a2.u[2]=ws+o_um; a2.v[2]=ws+o_vm; a2.out[2]=ws+o_wm;
  a2.W[3]=Wo; a2.u[3]=ws+o_uo; a2.v[3]=ws+o_vo; a2.out[3]=ws+o_wo;
  w2_kernel<<<256, BLK, 0, stream>>>(a2);

  for (int b0 = 0; b0 < 64; b0 += nb){
    gather_x_kernel<<<grid_for((long long)nb*2048), BLK, 0, stream>>>(ids, lat, ws+o_A, b0, nb);
    int H = 16;
    for (int s = 0; s < 4; ++s){
      int Ho = 2*H;
      int maps = nb*8;
      long long totalo = (long long)maps*Ho*Ho;
      int stR = max(1, (H*H)/2048);
      int stT = max(1, (Ho*Ho)/2048);
      int stM = max(1, (Ho*Ho)/2048);
      init_min_kernel<<<(3*maps + BLK-1)/BLK, BLK, 0, stream>>>(mn, 3*maps);
      convr_kernel<<<maps*stR, BLK, 0, stream>>>(ws+o_A, ws+o_wr, ws+o_br, ws+o_D, mn,          H, b0, s, stR);
      convt_kernel<<<maps*stT, BLK, 0, stream>>>(ws+o_A, ws+o_wt, ws+o_bt, ws+o_B, mn + maps,   H, b0, s, stT);
      uplog_kernel<<<grid_for(totalo), BLK, 0, stream>>>(ws+o_A, ws+o_C1, H, (int)totalo);
      convm_kernel<<<maps*stM, BLK, 0, stream>>>(ws+o_C1, ws+o_wm, ws+o_bm, ws+o_C2, mn + 2*maps, Ho, b0, s, stM);
      combine_kernel<<<grid_for(totalo), BLK, 0, stream>>>(ws+o_D, ws+o_B, ws+o_C2, mn, maps, ws+o_A, H, (int)totalo);
      H = Ho;
    }
    long long totalf = (long long)nb*3*65536;
    final_kernel<<<grid_for(totalf), BLK, 0, stream>>>(ws+o_A, ws+o_wo, ws+o_bo, out, b0, (int)totalf);
  }
}

// Round 4
// 3067.336 us; speedup vs baseline: 3.0736x; 1.5146x over previous
//
#include <hip/hip_runtime.h>
#include <math.h>

// ExperimentalModel_1752346656819: 4-stage dynamic-conv decoder, fp32 end-to-end.
// R2 (resubmitted after infra flake): LDS-tiled convs computing all 8 output
// channels per block (8x input reuse), zero-filled halos (no bounds checks),
// shfl-xor + atomicMin for per-map min, logf hoisted out of uplog.

#define BLK 256
#define EF 2.7182818284590452f

struct W1Args { const float* M[12]; float* out[12]; };
struct W2Args { const float* W[4]; const float* u[4]; const float* v[4]; float* out[4]; };

__device__ __forceinline__ float dln_one(float y, float m){
  float a = fabsf(y) - m;
  float v = logf(logf(a + EF) + 0.01f);
  return (y > 0.0f) ? v : -v;
}

__global__ void gather_ctx_kernel(const int* __restrict__ ids,
                                  const float* __restrict__ cache,
                                  float* __restrict__ ctx){
  int e = blockIdx.x*blockDim.x + threadIdx.x;
  if (e < 64*32){
    int b = e >> 5, l = e & 31;
    ctx[e] = cache[(size_t)ids[b]*32 + l];
  }
}

// gathers latents AND writes L = log(|x|+1) for the first uplog
__global__ void gather_x_kernel(const int* __restrict__ ids,
                                const float* __restrict__ lat,
                                float* __restrict__ A, float* __restrict__ L,
                                int b0, int nb){
  int total = nb*2048;
  int e = blockIdx.x*blockDim.x + threadIdx.x;
  if (e < total){
    int bl = e >> 11;
    int r  = e & 2047;
    float v = lat[(size_t)ids[b0+bl]*2048 + r];
    A[e] = v;
    L[e] = logf(fabsf(v) + 1.0f);
  }
}

__global__ void w1_kernel(const float* __restrict__ ctx, W1Args args){
  const int S[12] = {4,4,4,4,4,4,4,4,4,1,1,1};
  const int K[12] = {128,1152,128,2048,128,3200,8,8,8,48,128,3};
  int tid = blockIdx.x*blockDim.x + threadIdx.x;
  int nth = gridDim.x*blockDim.x;
  for (int seg = 0; seg < 12; ++seg){
    const float* M = args.M[seg];
    float* out = args.out[seg];
    int Ks = K[seg];
    int total = S[seg]*64*Ks;
    for (int e = tid; e < total; e += nth){
      int k = e % Ks;
      int b = (e / Ks) % 64;
      int s = e / (Ks*64);
      const float* Ms = M + (size_t)s*32*Ks + k;
      const float* cb = ctx + b*32;
      float acc = 0.f;
      #pragma unroll
      for (int l = 0; l < 32; ++l) acc += cb[l]*Ms[(size_t)l*Ks];
      out[e] = acc;
    }
  }
}

__global__ void w2_kernel(W2Args args){
  const int S[4] = {4,4,4,1};
  const int O[4] = {8,8,8,3};
  const int K[4] = {72,128,200,8};
  int tid = blockIdx.x*blockDim.x + threadIdx.x;
  int nth = gridDim.x*blockDim.x;
  for (int seg = 0; seg < 4; ++seg){
    int Os = O[seg], Ks = K[seg];
    int total = S[seg]*64*Os*Ks;
    const float* Wt = args.W[seg];
    const float* u = args.u[seg];
    const float* v = args.v[seg];
    float* out = args.out[seg];
    for (int e = tid; e < total; e += nth){
      int k = e % Ks;
      int o = (e/Ks) % Os;
      int b = (e/(Ks*Os)) % 64;
      int s = e/(Ks*Os*64);
      const float* us = u + (size_t)(s*64+b)*16*Os;
      const float* vs = v + (size_t)(s*64+b)*16*Ks;
      float mod = 0.f;
      #pragma unroll
      for (int r = 0; r < 16; ++r) mod += us[r*Os+o]*vs[r*Ks+k];
      out[e] = Wt[(size_t)(s*Os+o)*Ks + k] * (1.0f + mod + 1e-3f);
    }
  }
}

__global__ void init_min_kernel(unsigned* __restrict__ mn, int n){
  int e = blockIdx.x*blockDim.x + threadIdx.x;
  if (e < n) mn[e] = 0x7F800000u;   // +inf
}

// 3x3 conv (pad 1). Block = 32x32 px tile, all 8 o. Tile: 34 rows x 36 stride x 8 ch.
__global__ void __launch_bounds__(BLK) convr_t8(
    const float* __restrict__ x, const float* __restrict__ wall,
    const float* __restrict__ ball, float* __restrict__ out,
    unsigned* __restrict__ mn, int H, int b0, int s, int tpr){
  __shared__ __align__(16) float tile[8*34*36];
  __shared__ float tw[8*72 + 8];
  const int tiles = tpr*tpr;
  const int bl = blockIdx.x / tiles;
  const int t  = blockIdx.x - bl*tiles;
  const int Y0 = (t/tpr)*32, X0 = (t - (t/tpr)*tpr)*32;
  const int bg = b0 + bl;
  const float* wp = wall + ((size_t)((s*64+bg)*8))*72;
  for (int e = threadIdx.x; e < 576; e += BLK) tw[e] = wp[e];
  if (threadIdx.x < 8) tw[576+threadIdx.x] = ball[(s*64+bg)*8 + threadIdx.x];
  const int HW = H*H;
  const float* xb = x + (size_t)bl*8*HW;
  for (int e = threadIdx.x; e < 8*34*36; e += BLK){
    int cc = e % 36; int rr = (e/36) % 34; int ch = e/(36*34);
    int gy = Y0 - 1 + rr, gx = X0 - 1 + cc;
    float v = 0.f;
    if (cc < 34 && (unsigned)gy < (unsigned)H && (unsigned)gx < (unsigned)H)
      v = xb[(size_t)ch*HW + gy*H + gx];
    tile[e] = v;
  }
  __syncthreads();
  const int tx = threadIdx.x & 7, ty = threadIdx.x >> 3;
  const bool act = (Y0+ty < H) && (X0+4*tx < H);  // only false when H==16
  float a[8][4];
  #pragma unroll
  for (int o = 0; o < 8; ++o){
    float b = tw[576+o];
    a[o][0]=b; a[o][1]=b; a[o][2]=b; a[o][3]=b;
  }
  #pragma unroll 1
  for (int i = 0; i < 8; ++i){
    const float* tch = tile + i*1224;
    #pragma unroll
    for (int p = 0; p < 3; ++p){
      const float* row = tch + (ty+p)*36 + 4*tx;
      float4 c0 = *(const float4*)row;
      float4 c1 = *(const float4*)(row+4);
      float c[8] = {c0.x,c0.y,c0.z,c0.w,c1.x,c1.y,c1.z,c1.w};
      #pragma unroll
      for (int o = 0; o < 8; ++o){
        const float* wv = tw + o*72 + i*9 + p*3;
        #pragma unroll
        for (int q = 0; q < 3; ++q){
          float wq = wv[q];
          a[o][0] += wq*c[q];   a[o][1] += wq*c[q+1];
          a[o][2] += wq*c[q+2]; a[o][3] += wq*c[q+3];
        }
      }
    }
  }
  float lm[8];
  #pragma unroll
  for (int o = 0; o < 8; ++o){
    float v = act ? fminf(fminf(fabsf(a[o][0]),fabsf(a[o][1])),
                          fminf(fabsf(a[o][2]),fabsf(a[o][3]))) : 3.4e38f;
    #pragma unroll
    for (int off = 32; off > 0; off >>= 1) v = fminf(v, __shfl_xor(v, off));
    lm[o] = v;
    if (act){
      *(float4*)(out + ((size_t)(bl*8+o))*HW + (Y0+ty)*H + X0 + 4*tx) =
          make_float4(a[o][0],a[o][1],a[o][2],a[o][3]);
    }
  }
  if ((threadIdx.x & 63) == 0){
    #pragma unroll
    for (int o = 0; o < 8; ++o) atomicMin(mn + bl*8 + o, __float_as_uint(lm[o]));
  }
}

// 4x4 stride-2 transposed conv of (-x) (pad 1). Block = 32x32 OUTPUT tile, all 8 o.
// Input tile: 18 rows x 20 stride x 8 ch (zero-filled halo).
__global__ void __launch_bounds__(BLK) convt_t8(
    const float* __restrict__ x, const float* __restrict__ wall,
    const float* __restrict__ ball, float* __restrict__ out,
    unsigned* __restrict__ mn, int H, int b0, int s, int tpr){
  __shared__ float tile[8*18*20];
  __shared__ float tw[8*128 + 8];
  const int tiles = tpr*tpr;
  const int bl = blockIdx.x / tiles;
  const int t  = blockIdx.x - bl*tiles;
  const int Y0 = (t/tpr)*32, X0 = (t - (t/tpr)*tpr)*32;  // output coords
  const int bg = b0 + bl;
  const float* wp = wall + ((size_t)((s*64+bg)*8))*128;
  for (int e = threadIdx.x; e < 1024; e += BLK) tw[e] = wp[e];
  if (threadIdx.x < 8) tw[1024+threadIdx.x] = ball[(s*64+bg)*8 + threadIdx.x];
  const int Ho = 2*H, HWo = Ho*Ho, HW = H*H;
  const float* xb = x + (size_t)bl*8*HW;
  const int ry0 = Y0/2 - 1, rx0 = X0/2 - 1;
  for (int e = threadIdx.x; e < 8*18*20; e += BLK){
    int cc = e % 20; int rr = (e/20) % 18; int ch = e/(20*18);
    int gy = ry0 + rr, gx = rx0 + cc;
    float v = 0.f;
    if (cc < 18 && (unsigned)gy < (unsigned)H && (unsigned)gx < (unsigned)H)
      v = xb[(size_t)ch*HW + gy*H + gx];
    tile[e] = v;
  }
  __syncthreads();
  const int tx = threadIdx.x & 7, ty = threadIdx.x >> 3;
  const int half = ty >> 1;
  const int yodd = ty & 1;
  const int pA = yodd ? 0 : 1, rA = yodd ? half+2 : half+1;
  const int pB = yodd ? 2 : 3, rB = yodd ? half+1 : half;
  float a[8][4];
  #pragma unroll
  for (int o = 0; o < 8; ++o){
    float b = tw[1024+o];
    a[o][0]=b; a[o][1]=b; a[o][2]=b; a[o][3]=b;
  }
  #pragma unroll 1
  for (int i = 0; i < 8; ++i){
    #pragma unroll
    for (int rt = 0; rt < 2; ++rt){
      const int p = rt ? pB : pA;
      const int ri = rt ? rB : rA;
      const float* rowp = tile + i*360 + ri*20 + 2*tx;
      float e0 = rowp[0], e1 = rowp[1], e2 = rowp[2], e3 = rowp[3];
      #pragma unroll
      for (int o = 0; o < 8; ++o){
        const float* wb = tw + o*128 + i*16 + p*4;
        float w1 = wb[1]; a[o][0] -= w1*e1; a[o][2] -= w1*e2;  // x even, q=1
        float w3 = wb[3]; a[o][0] -= w3*e0; a[o][2] -= w3*e1;  // x even, q=3
        float w0 = wb[0]; a[o][1] -= w0*e2; a[o][3] -= w0*e3;  // x odd,  q=0
        float w2 = wb[2]; a[o][1] -= w2*e1; a[o][3] -= w2*e2;  // x odd,  q=2
      }
    }
  }
  float lm[8];
  #pragma unroll
  for (int o = 0; o < 8; ++o){
    float v = fminf(fminf(fabsf(a[o][0]),fabsf(a[o][1])),
                    fminf(fabsf(a[o][2]),fabsf(a[o][3])));
    #pragma unroll
    for (int off = 32; off > 0; off >>= 1) v = fminf(v, __shfl_xor(v, off));
    lm[o] = v;
    *(float4*)(out + ((size_t)(bl*8+o))*HWo + (Y0+ty)*Ho + X0 + 4*tx) =
        make_float4(a[o][0],a[o][1],a[o][2],a[o][3]);
  }
  if ((threadIdx.x & 63) == 0){
    #pragma unroll
    for (int o = 0; o < 8; ++o) atomicMin(mn + bl*8 + o, __float_as_uint(lm[o]));
  }
}

// bilinear 2x upsample of precomputed L = log(|x|+1)
__global__ void uplog_kernel(const float* __restrict__ L, float* __restrict__ out,
                             int H, int total){
  int Ho = 2*H, HWo = Ho*Ho, HW = H*H;
  for (int e = blockIdx.x*blockDim.x + threadIdx.x; e < total; e += gridDim.x*blockDim.x){
    int m = e / HWo;
    int px = e - m*HWo;
    int y = px / Ho, xx = px - y*Ho;
    const float* xm = L + (size_t)m*HW;
    int jy = y >> 1, jx = xx >> 1;
    int ny = (y & 1)  ? ((jy+1 < H) ? jy+1 : H-1) : ((jy > 0) ? jy-1 : 0);
    int nx = (xx & 1) ? ((jx+1 < H) ? jx+1 : H-1) : ((jx > 0) ? jx-1 : 0);
    float f00 = xm[jy*H + jx];
    float f01 = xm[jy*H + nx];
    float f10 = xm[ny*H + jx];
    float f11 = xm[ny*H + nx];
    out[e] = 0.5625f*f00 + 0.1875f*(f01 + f10) + 0.0625f*f11;
  }
}

// 5x5 conv (pad 2) on Hi x Hi. Block = 32x32 px tile, all 8 o. Tile: 36 x 40 x 8.
__global__ void __launch_bounds__(BLK) convm_t8(
    const float* __restrict__ x, const float* __restrict__ wall,
    const float* __restrict__ ball, float* __restrict__ out,
    unsigned* __restrict__ mn, int Hi, int b0, int s, int tpr){
  __shared__ __align__(16) float tile[8*36*40];
  __shared__ float tw[8*200 + 8];
  const int tiles = tpr*tpr;
  const int bl = blockIdx.x / tiles;
  const int t  = blockIdx.x - bl*tiles;
  const int Y0 = (t/tpr)*32, X0 = (t - (t/tpr)*tpr)*32;
  const int bg = b0 + bl;
  const float* wp = wall + ((size_t)((s*64+bg)*8))*200;
  for (int e = threadIdx.x; e < 1600; e += BLK) tw[e] = wp[e];
  if (threadIdx.x < 8) tw[1600+threadIdx.x] = ball[(s*64+bg)*8 + threadIdx.x];
  const int HW = Hi*Hi;
  const float* xb = x + (size_t)bl*8*HW;
  for (int e = threadIdx.x; e < 8*36*40; e += BLK){
    int cc = e % 40; int rr = (e/40) % 36; int ch = e/(40*36);
    int gy = Y0 - 2 + rr, gx = X0 - 2 + cc;
    float v = 0.f;
    if (cc < 36 && (unsigned)gy < (unsigned)Hi && (unsigned)gx < (unsigned)Hi)
      v = xb[(size_t)ch*HW + gy*Hi + gx];
    tile[e] = v;
  }
  __syncthreads();
  const int tx = threadIdx.x & 7, ty = threadIdx.x >> 3;
  float a[8][4];
  #pragma unroll
  for (int o = 0; o < 8; ++o){
    float b = tw[1600+o];
    a[o][0]=b; a[o][1]=b; a[o][2]=b; a[o][3]=b;
  }
  #pragma unroll 1
  for (int i = 0; i < 8; ++i){
    const float* tch = tile + i*1440;
    #pragma unroll
    for (int p = 0; p < 5; ++p){
      const float* row = tch + (ty+p)*40 + 4*tx;
      float4 c0 = *(const float4*)row;
      float4 c1 = *(const float4*)(row+4);
      float c[8] = {c0.x,c0.y,c0.z,c0.w,c1.x,c1.y,c1.z,c1.w};
      #pragma unroll
      for (int o = 0; o < 8; ++o){
        const float* wv = tw + o*200 + i*25 + p*5;
        #pragma unroll
        for (int q = 0; q < 5; ++q){
          float wq = wv[q];
          a[o][0] += wq*c[q];   a[o][1] += wq*c[q+1];
          a[o][2] += wq*c[q+2]; a[o][3] += wq*c[q+3];
        }
      }
    }
  }
  float lm[8];
  #pragma unroll
  for (int o = 0; o < 8; ++o){
    float v = fminf(fminf(fabsf(a[o][0]),fabsf(a[o][1])),
                    fminf(fabsf(a[o][2]),fabsf(a[o][3])));
    #pragma unroll
    for (int off = 32; off > 0; off >>= 1) v = fminf(v, __shfl_xor(v, off));
    lm[o] = v;
    *(float4*)(out + ((size_t)(bl*8+o))*HW + (Y0+ty)*Hi + X0 + 4*tx) =
        make_float4(a[o][0],a[o][1],a[o][2],a[o][3]);
  }
  if ((threadIdx.x & 63) == 0){
    #pragma unroll
    for (int o = 0; o < 8; ++o) atomicMin(mn + bl*8 + o, __float_as_uint(lm[o]));
  }
}

// next_x = (dln(Dr)[nearest-up] + dln(Dt)) * dln(Dm); optionally also L = log(|v|+1)
__global__ void combine_kernel(const float* __restrict__ dr, const float* __restrict__ dt,
                               const float* __restrict__ dm,
                               const unsigned* __restrict__ mn, int maps,
                               float* __restrict__ outx, float* __restrict__ Lout,
                               int H, int total, int writeL){
  int Ho = 2*H, HWo = Ho*Ho, HW = H*H;
  for (int e = blockIdx.x*blockDim.x + threadIdx.x; e < total; e += gridDim.x*blockDim.x){
    int m = e / HWo;
    int px = e - m*HWo;
    int y = px / Ho, xx = px - y*Ho;
    float mr = __uint_as_float(mn[m]);
    float mt = __uint_as_float(mn[maps + m]);
    float mm = __uint_as_float(mn[2*maps + m]);
    float r = dln_one(dr[(size_t)m*HW + (y >> 1)*H + (xx >> 1)], mr);
    float t = dln_one(dt[e], mt);
    float mv = dln_one(dm[e], mm);
    float v = (r + t) * mv;
    outx[e] = v;
    if (writeL) Lout[e] = logf(fabsf(v) + 1.0f);
  }
}

__global__ void final_kernel(const float* __restrict__ x, const float* __restrict__ wo,
                             const float* __restrict__ bo, float* __restrict__ out,
                             int b0, int total){
  for (int e = blockIdx.x*blockDim.x + threadIdx.x; e < total; e += gridDim.x*blockDim.x){
    int px = e & 65535;
    int t = e >> 16;
    int o = t % 3;
    int bl = t / 3;
    int bg = b0 + bl;
    const float* xb = x + ((size_t)bl*8)*65536 + px;
    const float* w = wo + bg*24 + o*8;
    float acc = bo[bg*3 + o];
    #pragma unroll
    for (int i = 0; i < 8; ++i) acc += w[i]*xb[(size_t)i*65536];
    out[((size_t)(bg*3 + o))*65536 + px] = acc;
  }
}

static inline int grid_for(long long total){
  long long g = (total + BLK - 1) / BLK;
  if (g > 16384) g = 16384;
  if (g < 1) g = 1;
  return (int)g;
}

extern "C" void kernel_launch(void* const* d_in, const int* in_sizes, int n_in,
                              void* d_out, int out_size, void* d_ws, size_t ws_size,
                              hipStream_t stream){
  (void)in_sizes; (void)n_in; (void)out_size;
  const int*   ids   = (const int*)d_in[0];
  const float* cache = (const float*)d_in[1];
  const float* lat   = (const float*)d_in[2];
  const float* Wr = (const float*)d_in[3];
  const float* Ur = (const float*)d_in[4];
  const float* Vr = (const float*)d_in[5];
  const float* Br = (const float*)d_in[6];
  const float* Wt = (const float*)d_in[7];
  const float* Ut = (const float*)d_in[8];
  const float* Vt = (const float*)d_in[9];
  const float* Bt = (const float*)d_in[10];
  const float* Wm = (const float*)d_in[11];
  const float* Um = (const float*)d_in[12];
  const float* Vm = (const float*)d_in[13];
  const float* Bm = (const float*)d_in[14];
  const float* Wo = (const float*)d_in[15];
  const float* Uo = (const float*)d_in[16];
  const float* Vo = (const float*)d_in[17];
  const float* Bo = (const float*)d_in[18];
  float* out = (float*)d_out;
  float* ws  = (float*)d_ws;

  size_t off = 0;
  auto alloc = [&](size_t n){ size_t o = off; off += n; return o; };
  size_t o_ctx = alloc(2048);
  size_t o_ur = alloc(4*64*128),  o_vr = alloc(4*64*1152);
  size_t o_ut = alloc(4*64*128),  o_vt = alloc(4*64*2048);
  size_t o_um = alloc(4*64*128),  o_vm = alloc(4*64*3200);
  size_t o_br = alloc(4*64*8), o_bt = alloc(4*64*8), o_bm = alloc(4*64*8);
  size_t o_uo = alloc(64*48), o_vo = alloc(64*128), o_bo = alloc(64*3);
  size_t o_wr = alloc(4*64*8*72), o_wt = alloc(4*64*8*128), o_wm = alloc(4*64*8*200);
  size_t o_wo = alloc(64*24);
  size_t o_mn = alloc(3*512);
  size_t small_end = off;

  // per-sample: A,B(Dt),C1(xup),C2(Dm) full (8*256^2) + D(Dr),L quarter (8*128^2)
  const size_t perS = 4*(size_t)524288 + 2*(size_t)131072;
  size_t ws_f = ws_size / sizeof(float);
  int nb = 64;
  while (nb > 1 && small_end + (size_t)nb*perS > ws_f) nb >>= 1;

  size_t o_A  = small_end;
  size_t o_B  = o_A  + (size_t)nb*524288;
  size_t o_C1 = o_B  + (size_t)nb*524288;
  size_t o_C2 = o_C1 + (size_t)nb*524288;
  size_t o_D  = o_C2 + (size_t)nb*524288;
  size_t o_L  = o_D  + (size_t)nb*131072;
  unsigned* mn = (unsigned*)(ws + o_mn);

  gather_ctx_kernel<<<8, BLK, 0, stream>>>(ids, cache, ws + o_ctx);

  W1Args a1;
  a1.M[0]=Ur;  a1.out[0]=ws+o_ur;
  a1.M[1]=Vr;  a1.out[1]=ws+o_vr;
  a1.M[2]=Ut;  a1.out[2]=ws+o_ut;
  a1.M[3]=Vt;  a1.out[3]=ws+o_vt;
  a1.M[4]=Um;  a1.out[4]=ws+o_um;
  a1.M[5]=Vm;  a1.out[5]=ws+o_vm;
  a1.M[6]=Br;  a1.out[6]=ws+o_br;
  a1.M[7]=Bt;  a1.out[7]=ws+o_bt;
  a1.M[8]=Bm;  a1.out[8]=ws+o_bm;
  a1.M[9]=Uo;  a1.out[9]=ws+o_uo;
  a1.M[10]=Vo; a1.out[10]=ws+o_vo;
  a1.M[11]=Bo; a1.out[11]=ws+o_bo;
  w1_kernel<<<256, BLK, 0, stream>>>(ws + o_ctx, a1);

  W2Args a2;
  a2.W[0]=Wr; a2.u[0]=ws+o_ur; a2.v[0]=ws+o_vr; a2.out[0]=ws+o_wr;
  a2.W[1]=Wt; a2.u[1]=ws+o_ut; a2.v[1]=ws+o_vt; a2.out[1]=ws+o_wt;
  a2.W[2]=Wm; a2.u[2]=ws+o_um; a2.v[2]=ws+o_vm; a2.out[2]=ws+o_wm;
  a2.W[3]=Wo; a2.u[3]=ws+o_uo; a2.v[3]=ws+o_vo; a2.out[3]=ws+o_wo;
  w2_kernel<<<256, BLK, 0, stream>>>(a2);

  for (int b0 = 0; b0 < 64; b0 += nb){
    gather_x_kernel<<<grid_for((long long)nb*2048), BLK, 0, stream>>>(
        ids, lat, ws+o_A, ws+o_L, b0, nb);
    int H = 16;
    for (int s = 0; s < 4; ++s){
      int Ho = 2*H;
      int maps = nb*8;
      long long totalo = (long long)maps*Ho*Ho;
      int tprR = (H >= 32) ? H/32 : 1;
      int tprO = Ho/32;
      init_min_kernel<<<(3*maps + BLK-1)/BLK, BLK, 0, stream>>>(mn, 3*maps);
      convr_t8<<<nb*tprR*tprR, BLK, 0, stream>>>(ws+o_A, ws+o_wr, ws+o_br, ws+o_D, mn,          H, b0, s, tprR);
      convt_t8<<<nb*tprO*tprO, BLK, 0, stream>>>(ws+o_A, ws+o_wt, ws+o_bt, ws+o_B, mn + maps,   H, b0, s, tprO);
      uplog_kernel<<<grid_for(totalo), BLK, 0, stream>>>(ws+o_L, ws+o_C1, H, (int)totalo);
      convm_t8<<<nb*tprO*tprO, BLK, 0, stream>>>(ws+o_C1, ws+o_wm, ws+o_bm, ws+o_C2, mn + 2*maps, Ho, b0, s, tprO);
      combine_kernel<<<grid_for(totalo), BLK, 0, stream>>>(
          ws+o_D, ws+o_B, ws+o_C2, mn, maps, ws+o_A, ws+o_L, H, (int)totalo, (s < 3) ? 1 : 0);
      H = Ho;
    }
    long long totalf = (long long)nb*3*65536;
    final_kernel<<<grid_for(totalf), BLK, 0, stream>>>(ws+o_A, ws+o_wo, ws+o_bo, out, b0, (int)totalf);
  }
}